// Round 2
// baseline (1708.926 us; speedup 1.0000x reference)
//
#include <hip/hip_runtime.h>

typedef unsigned short u16;
typedef unsigned int u32;
typedef short short8v __attribute__((ext_vector_type(8)));
typedef float float4v __attribute__((ext_vector_type(4)));

#define N_NODES 50000
#define E_EDGES 400000
#define R_REL   500

__device__ __forceinline__ float bl(u32 u){ return __uint_as_float(u << 16); }
__device__ __forceinline__ float bh(u32 u){ return __uint_as_float(u & 0xffff0000u); }
__device__ __forceinline__ u16 f2b(float f){
    u32 u = __float_as_uint(f);
    return (u16)((u + 0x7fffu + ((u >> 16) & 1u)) >> 16);
}
__device__ __forceinline__ u32 pk2(float a, float b){ return (u32)f2b(a) | ((u32)f2b(b) << 16); }
__device__ __forceinline__ float lrelu(float x){ return x > 0.f ? x : 0.01f * x; }

// ---------------- normalize x -> bf16 padded [N,128] ----------------
__global__ void k_norm_x(const float* __restrict__ x, u16* __restrict__ xnb){
    int wid = threadIdx.x >> 6, l = threadIdx.x & 63;
    int n = blockIdx.x * 4 + wid;
    if (n >= N_NODES) return;
    float v0 = x[(size_t)n * 100 + l];                       // l < 64 < 100
    float v1 = (l + 64 < 100) ? x[(size_t)n * 100 + 64 + l] : 0.f;
    float ss = v0 * v0 + v1 * v1;
    #pragma unroll
    for (int m = 32; m; m >>= 1) ss += __shfl_xor(ss, m);
    float s = 1.f / fmaxf(sqrtf(ss), 1e-12f);
    xnb[(size_t)n * 128 + l] = f2b(v0 * s);
    xnb[(size_t)n * 128 + 64 + l] = (l + 64 < 100) ? f2b(v1 * s) : (u16)0;
}

// ---------------- build concatenated weight matrices (bf16) ----------------
// wc1 [576,128]: rows 0-127 W1i[:,0:100] | 128-255 W1i[:,100:200] | 256-383 W1o[:,0:100]
//                | 384-511 W1o[:,100:200] | 512-575 We[:,0:100]   (k>=100 zero-padded)
// wc2 [512,128]: W2i[:,0:128] | W2i[:,128:256] | W2o[:,0:128] | W2o[:,128:256]
__global__ void k_build_wcat(const float* __restrict__ W1i, const float* __restrict__ W1o,
                             const float* __restrict__ W2i, const float* __restrict__ W2o,
                             const float* __restrict__ We,
                             u16* __restrict__ wc1, u16* __restrict__ wc2){
    int idx = blockIdx.x * blockDim.x + threadIdx.x;
    if (idx < 576 * 128){
        int r = idx >> 7, k = idx & 127;
        float v = 0.f;
        if (r < 512){
            int seg = r >> 7, rr = r & 127;
            const float* W = (seg < 2) ? W1i : W1o;
            int off = (seg & 1) ? 100 : 0;
            if (k < 100) v = W[(size_t)rr * 300 + off + k];
        } else {
            int rr = r - 512;
            if (k < 100) v = We[(size_t)rr * 100 + k];
        }
        wc1[idx] = f2b(v);
    } else if (idx < 576 * 128 + 512 * 128){
        int j = idx - 576 * 128;
        int r = j >> 7, k = j & 127;
        int seg = r >> 7, rr = r & 127;
        const float* W = (seg < 2) ? W2i : W2o;
        int off = (seg & 1) ? 128 : 0;
        wc2[j] = f2b(W[(size_t)rr * 356 + off + k]);
    }
}

// ---------------- relation tables: Pg[t][r][128] = g[r]·Wg_t^T + b_t ; qg[t][r][h] ----------------
__global__ void k_pg(const float* __restrict__ g,
                     const float* __restrict__ W1i, const float* __restrict__ W1o,
                     const float* __restrict__ W2i, const float* __restrict__ W2o,
                     const float* __restrict__ b1i, const float* __restrict__ b1o,
                     const float* __restrict__ b2i, const float* __restrict__ b2o,
                     const float* __restrict__ a1i, const float* __restrict__ a1o,
                     const float* __restrict__ a2i, const float* __restrict__ a2o,
                     float* __restrict__ Pg, float* __restrict__ qg){
    int bid = blockIdx.x;
    int r = bid >> 2, t = bid & 3;
    const float *W, *b, *att; int ld, off;
    if (t == 0){ W = W1i; ld = 300; off = 200; b = b1i; att = a1i; }
    else if (t == 1){ W = W1o; ld = 300; off = 200; b = b1o; att = a1o; }
    else if (t == 2){ W = W2i; ld = 356; off = 256; b = b2i; att = a2i; }
    else { W = W2o; ld = 356; off = 256; b = b2o; att = a2o; }
    __shared__ float gs[100];
    __shared__ float red[128];
    int j = threadIdx.x; // 128 threads
    if (j < 100) gs[j] = g[(size_t)r * 100 + j];
    __syncthreads();
    float acc = b[j];
    #pragma unroll 4
    for (int k = 0; k < 100; ++k) acc += gs[k] * W[(size_t)j * ld + off + k];
    Pg[((size_t)t * R_REL + r) * 128 + j] = acc;
    red[j] = att[j] * acc;
    __syncthreads();
    if (j < 2){
        float s = 0.f;
        for (int k = 0; k < 64; ++k) s += red[j * 64 + k];
        qg[((size_t)t * R_REL + r) * 2 + j] = s;
    }
}

// ---------------- g_prime = g @ Wr^T + br -> out (f32) ----------------
__global__ void k_gprime(const float* __restrict__ g, const float* __restrict__ Wr,
                         const float* __restrict__ br, float* __restrict__ out){
    int r = blockIdx.x, j = threadIdx.x; // 128 threads
    __shared__ float gs[100];
    if (j < 100) gs[j] = g[(size_t)r * 100 + j];
    __syncthreads();
    float acc = br[j];
    #pragma unroll 4
    for (int k = 0; k < 100; ++k) acc += gs[k] * Wr[(size_t)j * 100 + k];
    out[(size_t)N_NODES * 128 + (size_t)r * 128 + j] = acc;
}

// ---------------- node GEMM: C[M,NN] = A[M,128] @ W[NN,128]^T  (bf16 in/out, MFMA) ----------------
__launch_bounds__(256)
__global__ void k_gemm(const u16* __restrict__ A, const u16* __restrict__ W,
                       u16* __restrict__ C, int M, int NN){
    int l = threadIdx.x & 63, w = threadIdx.x >> 6;
    int rb = blockIdx.x * 64 + w * 16;
    int ar = rb + (l & 15); if (ar >= M) ar = M - 1;
    const u16* Ap = A + (size_t)ar * 128 + (l >> 4) * 8;
    short8v a0 = *(const short8v*)(Ap);
    short8v a1 = *(const short8v*)(Ap + 32);
    short8v a2 = *(const short8v*)(Ap + 64);
    short8v a3 = *(const short8v*)(Ap + 96);
    int ntc = NN >> 4;
    for (int nt = 0; nt < ntc; ++nt){
        const u16* Wp = W + (size_t)(nt * 16 + (l & 15)) * 128 + (l >> 4) * 8;
        short8v b0 = *(const short8v*)(Wp);
        short8v b1 = *(const short8v*)(Wp + 32);
        short8v b2 = *(const short8v*)(Wp + 64);
        short8v b3 = *(const short8v*)(Wp + 96);
        float4v acc = {0.f, 0.f, 0.f, 0.f};
        acc = __builtin_amdgcn_mfma_f32_16x16x32_bf16(a0, b0, acc, 0, 0, 0);
        acc = __builtin_amdgcn_mfma_f32_16x16x32_bf16(a1, b1, acc, 0, 0, 0);
        acc = __builtin_amdgcn_mfma_f32_16x16x32_bf16(a2, b2, acc, 0, 0, 0);
        acc = __builtin_amdgcn_mfma_f32_16x16x32_bf16(a3, b3, acc, 0, 0, 0);
        int cc = nt * 16 + (l & 15);
        int rr0 = rb + (l >> 4) * 4;
        #pragma unroll
        for (int r = 0; r < 4; ++r){
            int rr = rr0 + r;
            if (rr < M) C[(size_t)rr * NN + cc] = f2b(acc[r]);
        }
    }
}

// ---------------- per-node attention scalars q[n][t*2+h] = att·P_t[n] ----------------
__global__ void k_qnode(const u16* __restrict__ NP, int stride,
                        const float* __restrict__ attI, const float* __restrict__ attO,
                        float* __restrict__ q){
    int wid = threadIdx.x >> 6, l = threadIdx.x & 63;
    int n = blockIdx.x * 4 + wid;
    if (n >= N_NODES) return;
    uint4 uv = *(const uint4*)(NP + (size_t)n * stride + (size_t)l * 8);
    int t = l >> 4, h = (l >> 3) & 1;
    const float* att = ((t < 2) ? attI : attO) + h * 64 + (l & 7) * 8;
    float s = bl(uv.x) * att[0] + bh(uv.x) * att[1] + bl(uv.y) * att[2] + bh(uv.y) * att[3]
            + bl(uv.z) * att[4] + bh(uv.z) * att[5] + bl(uv.w) * att[6] + bh(uv.w) * att[7];
    s += __shfl_xor(s, 1); s += __shfl_xor(s, 2); s += __shfl_xor(s, 4);
    if ((l & 7) == 0) q[(size_t)n * 8 + t * 2 + h] = s;
}

// ---------------- edge pass A: logits -> exp -> denominators ----------------
__global__ void k_edgeA(const int* __restrict__ ei, const int* __restrict__ ety,
                        const float* __restrict__ q,
                        const float* __restrict__ qgI, const float* __restrict__ qgO,
                        float* __restrict__ ee, float* __restrict__ dI, float* __restrict__ dO){
    int e = blockIdx.x * blockDim.x + threadIdx.x;
    if (e >= E_EDGES) return;
    int row = ei[e], col = ei[E_EDGES + e], et = ety[e];
    const float* qr = q + (size_t)row * 8;
    const float* qc = q + (size_t)col * 8;
    const float* gI = qgI + (size_t)et * 2;
    const float* gO = qgO + (size_t)et * 2;
    #pragma unroll
    for (int h = 0; h < 2; ++h){
        float ain = qr[h] + qc[2 + h] + gI[h];               // att_i·(Pa_i[row]+Pb_i[col]+Pg_i[et]+b)
        float ein = expf(lrelu(ain));
        ee[(size_t)e * 4 + h] = ein;
        unsafeAtomicAdd(&dI[(size_t)row * 2 + h], ein);
        float aout = qc[4 + h] + qr[6 + h] + gO[h];          // att_o·(Pa_o[col]+Pb_o[row]+Pg_o[et]+b)
        float eout = expf(lrelu(aout));
        ee[(size_t)e * 4 + 2 + h] = eout;
        unsafeAtomicAdd(&dO[(size_t)col * 2 + h], eout);
    }
}

// ---------------- edge pass B: hacc[col] += .5*ain*c_in ; hacc[row] += .5*aout*c_out ----------------
__global__ void k_edgeB(const int* __restrict__ ei, const int* __restrict__ ety,
                        const u16* __restrict__ NP, int stride,
                        const float* __restrict__ PgI, const float* __restrict__ PgO,
                        const float* __restrict__ ee,
                        const float* __restrict__ dI, const float* __restrict__ dO,
                        float* __restrict__ hacc){
    int wid = threadIdx.x >> 6, l = threadIdx.x & 63;
    int e = blockIdx.x * 4 + wid;
    if (e >= E_EDGES) return;
    int row = ei[e], col = ei[E_EDGES + e], et = ety[e];
    int h = l >> 5, d0 = l * 2;
    float ai = ee[(size_t)e * 4 + h] / dI[(size_t)row * 2 + h];
    float ao = ee[(size_t)e * 4 + 2 + h] / dO[(size_t)col * 2 + h];
    const u16* rowP = NP + (size_t)row * stride;
    const u16* colP = NP + (size_t)col * stride;
    u32 pai = *(const u32*)(rowP + d0);
    u32 pbi = *(const u32*)(colP + 128 + d0);
    u32 pao = *(const u32*)(colP + 256 + d0);
    u32 pbo = *(const u32*)(rowP + 384 + d0);
    const float* gI = PgI + (size_t)et * 128 + d0;
    const float* gO = PgO + (size_t)et * 128 + d0;
    float cin0 = bl(pai) + bl(pbi) + gI[0];
    float cin1 = bh(pai) + bh(pbi) + gI[1];
    float cot0 = bl(pao) + bl(pbo) + gO[0];
    float cot1 = bh(pao) + bh(pbo) + gO[1];
    float* hc = hacc + (size_t)col * 128 + d0;
    float* hr = hacc + (size_t)row * 128 + d0;
    unsafeAtomicAdd(hc,     0.5f * ai * cin0);
    unsafeAtomicAdd(hc + 1, 0.5f * ai * cin1);
    unsafeAtomicAdd(hr,     0.5f * ao * cot0);
    unsafeAtomicAdd(hr + 1, 0.5f * ao * cot1);
}

// ---------------- stage-1 node pass: lrelu + per-head L2 norm -> h1 (bf16) ----------------
__global__ void k_node1(const float* __restrict__ hacc, u16* __restrict__ h1b){
    int wid = threadIdx.x >> 6, l = threadIdx.x & 63;
    int n = blockIdx.x * 4 + wid;
    if (n >= N_NODES) return;
    float2 v = *(const float2*)(hacc + (size_t)n * 128 + l * 2);
    v.x = lrelu(v.x); v.y = lrelu(v.y);
    float ss = v.x * v.x + v.y * v.y;
    #pragma unroll
    for (int m = 16; m; m >>= 1) ss += __shfl_xor(ss, m);   // per-head (32-lane) reduce
    float s = 1.f / fmaxf(sqrtf(ss), 1e-12f);
    *(u32*)(h1b + (size_t)n * 128 + l * 2) = pk2(v.x * s, v.y * s);
}

// ---------------- final: stage-2 node pass + entity + full-row norm -> out (f32) ----------------
__global__ void k_final(const float* __restrict__ hacc, const u16* __restrict__ NP1,
                        const float* __restrict__ be, float* __restrict__ out){
    int wid = threadIdx.x >> 6, l = threadIdx.x & 63;
    int n = blockIdx.x * 4 + wid;
    if (n >= N_NODES) return;
    float2 v = *(const float2*)(hacc + (size_t)n * 128 + l * 2);
    v.x = lrelu(v.x); v.y = lrelu(v.y);
    float ss = v.x * v.x + v.y * v.y;
    #pragma unroll
    for (int m = 16; m; m >>= 1) ss += __shfl_xor(ss, m);   // per-head norm
    float s2 = 1.f / fmaxf(sqrtf(ss), 1e-12f);
    float h20 = v.x * s2, h21 = v.y * s2;
    int o0 = (l * 2) & 63;
    u32 ue = *(const u32*)(NP1 + (size_t)n * 576 + 512 + o0);
    float hp0 = bl(ue) + be[o0] + h20;
    float hp1 = bh(ue) + be[o0 + 1] + h21;
    float st = hp0 * hp0 + hp1 * hp1;
    #pragma unroll
    for (int m = 32; m; m >>= 1) st += __shfl_xor(st, m);   // full 128-dim norm
    float s = 1.f / fmaxf(sqrtf(st), 1e-12f);
    float2 o; o.x = hp0 * s; o.y = hp1 * s;
    *(float2*)(out + (size_t)n * 128 + l * 2) = o;
}

extern "C" void kernel_launch(void* const* d_in, const int* in_sizes, int n_in,
                              void* d_out, int out_size, void* d_ws, size_t ws_size,
                              hipStream_t stream){
    const float* x   = (const float*)d_in[0];
    const float* g   = (const float*)d_in[1];
    const int*   ei  = (const int*)d_in[2];
    const int*   ety = (const int*)d_in[3];
    const float* W1i = (const float*)d_in[4];
    const float* b1i = (const float*)d_in[5];
    const float* a1i = (const float*)d_in[6];
    const float* W1o = (const float*)d_in[7];
    const float* b1o = (const float*)d_in[8];
    const float* a1o = (const float*)d_in[9];
    const float* W2i = (const float*)d_in[10];
    const float* b2i = (const float*)d_in[11];
    const float* a2i = (const float*)d_in[12];
    const float* W2o = (const float*)d_in[13];
    const float* b2o = (const float*)d_in[14];
    const float* a2o = (const float*)d_in[15];
    const float* We  = (const float*)d_in[16];
    const float* be  = (const float*)d_in[17];
    const float* Wr  = (const float*)d_in[18];
    const float* br  = (const float*)d_in[19];
    float* out = (float*)d_out;

    char* ws = (char*)d_ws;
    size_t off = 0;
    auto carve = [&](size_t bytes) -> char* {
        char* p = ws + off;
        off += (bytes + 255) & ~(size_t)255;
        return p;
    };
    u16*   xnb = (u16*)carve((size_t)N_NODES * 128 * 2);
    u16*   wc1 = (u16*)carve((size_t)576 * 128 * 2);
    u16*   wc2 = (u16*)carve((size_t)512 * 128 * 2);
    u16*   NP1 = (u16*)carve((size_t)N_NODES * 576 * 2);
    u16*   NP2 = (u16*)carve((size_t)N_NODES * 512 * 2);
    u16*   h1b = (u16*)carve((size_t)N_NODES * 128 * 2);
    float* q   = (float*)carve((size_t)N_NODES * 8 * 4);
    float* Pg  = (float*)carve((size_t)4 * R_REL * 128 * 4);
    float* qg  = (float*)carve((size_t)4 * R_REL * 2 * 4);
    float* ee  = (float*)carve((size_t)E_EDGES * 4 * 4);
    // contiguous zero region: dI | dO | hacc
    size_t zbytes = (size_t)N_NODES * 2 * 4 + (size_t)N_NODES * 2 * 4 + (size_t)N_NODES * 128 * 4;
    char*  zreg = carve(zbytes);
    float* dI   = (float*)zreg;
    float* dO   = dI + (size_t)N_NODES * 2;
    float* hacc = dO + (size_t)N_NODES * 2;

    // ---------------- stage 0: prep ----------------
    hipMemsetAsync(zreg, 0, zbytes, stream);
    k_norm_x<<<12500, 256, 0, stream>>>(x, xnb);
    k_build_wcat<<<544, 256, 0, stream>>>(W1i, W1o, W2i, W2o, We, wc1, wc2);
    k_pg<<<2000, 128, 0, stream>>>(g, W1i, W1o, W2i, W2o, b1i, b1o, b2i, b2o,
                                   a1i, a1o, a2i, a2o, Pg, qg);
    k_gprime<<<500, 128, 0, stream>>>(g, Wr, br, out);

    // ---------------- stage 1 ----------------
    k_gemm<<<782, 256, 0, stream>>>(xnb, wc1, NP1, N_NODES, 576);
    k_qnode<<<12500, 256, 0, stream>>>(NP1, 576, a1i, a1o, q);
    k_edgeA<<<1563, 256, 0, stream>>>(ei, ety, q, qg, qg + R_REL * 2, ee, dI, dO);
    k_edgeB<<<100000, 256, 0, stream>>>(ei, ety, NP1, 576, Pg, Pg + R_REL * 128,
                                        ee, dI, dO, hacc);
    k_node1<<<12500, 256, 0, stream>>>(hacc, h1b);

    // ---------------- stage 2 ----------------
    hipMemsetAsync(zreg, 0, zbytes, stream);
    k_gemm<<<782, 256, 0, stream>>>(h1b, wc2, NP2, N_NODES, 512);
    k_qnode<<<12500, 256, 0, stream>>>(NP2, 512, a2i, a2o, q);
    k_edgeA<<<1563, 256, 0, stream>>>(ei, ety, q, qg + 2 * R_REL * 2, qg + 3 * R_REL * 2,
                                      ee, dI, dO);
    k_edgeB<<<100000, 256, 0, stream>>>(ei, ety, NP2, 512, Pg + 2 * R_REL * 128,
                                        Pg + 3 * R_REL * 128, ee, dI, dO, hacc);
    k_final<<<12500, 256, 0, stream>>>(hacc, NP1, be, out);
}

// Round 3
// 734.156 us; speedup vs baseline: 2.3277x; 2.3277x over previous
//
#include <hip/hip_runtime.h>

typedef unsigned short u16;
typedef unsigned int u32;
typedef short short8v __attribute__((ext_vector_type(8)));
typedef float float4v __attribute__((ext_vector_type(4)));

#define N_NODES 50000
#define E_EDGES 400000
#define R_REL   500
#define NKEYS   100000          // cntI[50000] | cntO[50000]
#define SCAN_B  98              // 98*1024 = 100352 >= NKEYS

__device__ __forceinline__ float bl(u32 u){ return __uint_as_float(u << 16); }
__device__ __forceinline__ float bh(u32 u){ return __uint_as_float(u & 0xffff0000u); }
__device__ __forceinline__ u16 f2b(float f){
    u32 u = __float_as_uint(f);
    return (u16)((u + 0x7fffu + ((u >> 16) & 1u)) >> 16);
}
__device__ __forceinline__ u32 pk2(float a, float b){ return (u32)f2b(a) | ((u32)f2b(b) << 16); }
__device__ __forceinline__ float lrelu(float x){ return x > 0.f ? x : 0.01f * x; }

// ---------------- normalize x -> bf16 padded [N,128] ----------------
__global__ void k_norm_x(const float* __restrict__ x, u16* __restrict__ xnb){
    int wid = threadIdx.x >> 6, l = threadIdx.x & 63;
    int n = blockIdx.x * 4 + wid;
    if (n >= N_NODES) return;
    float v0 = x[(size_t)n * 100 + l];
    float v1 = (l + 64 < 100) ? x[(size_t)n * 100 + 64 + l] : 0.f;
    float ss = v0 * v0 + v1 * v1;
    #pragma unroll
    for (int m = 32; m; m >>= 1) ss += __shfl_xor(ss, m);
    float s = 1.f / fmaxf(sqrtf(ss), 1e-12f);
    xnb[(size_t)n * 128 + l] = f2b(v0 * s);
    xnb[(size_t)n * 128 + 64 + l] = (l + 64 < 100) ? f2b(v1 * s) : (u16)0;
}

// ---------------- build concatenated weight matrices (bf16) ----------------
__global__ void k_build_wcat(const float* __restrict__ W1i, const float* __restrict__ W1o,
                             const float* __restrict__ W2i, const float* __restrict__ W2o,
                             const float* __restrict__ We,
                             u16* __restrict__ wc1, u16* __restrict__ wc2){
    int idx = blockIdx.x * blockDim.x + threadIdx.x;
    if (idx < 576 * 128){
        int r = idx >> 7, k = idx & 127;
        float v = 0.f;
        if (r < 512){
            int seg = r >> 7, rr = r & 127;
            const float* W = (seg < 2) ? W1i : W1o;
            int off = (seg & 1) ? 100 : 0;
            if (k < 100) v = W[(size_t)rr * 300 + off + k];
        } else {
            int rr = r - 512;
            if (k < 100) v = We[(size_t)rr * 100 + k];
        }
        wc1[idx] = f2b(v);
    } else if (idx < 576 * 128 + 512 * 128){
        int j = idx - 576 * 128;
        int r = j >> 7, k = j & 127;
        int seg = r >> 7, rr = r & 127;
        const float* W = (seg < 2) ? W2i : W2o;
        int off = (seg & 1) ? 128 : 0;
        wc2[j] = f2b(W[(size_t)rr * 356 + off + k]);
    }
}

// ---------------- relation tables ----------------
__global__ void k_pg(const float* __restrict__ g,
                     const float* __restrict__ W1i, const float* __restrict__ W1o,
                     const float* __restrict__ W2i, const float* __restrict__ W2o,
                     const float* __restrict__ b1i, const float* __restrict__ b1o,
                     const float* __restrict__ b2i, const float* __restrict__ b2o,
                     const float* __restrict__ a1i, const float* __restrict__ a1o,
                     const float* __restrict__ a2i, const float* __restrict__ a2o,
                     float* __restrict__ Pg, float* __restrict__ qg){
    int bid = blockIdx.x;
    int r = bid >> 2, t = bid & 3;
    const float *W, *b, *att; int ld, off;
    if (t == 0){ W = W1i; ld = 300; off = 200; b = b1i; att = a1i; }
    else if (t == 1){ W = W1o; ld = 300; off = 200; b = b1o; att = a1o; }
    else if (t == 2){ W = W2i; ld = 356; off = 256; b = b2i; att = a2i; }
    else { W = W2o; ld = 356; off = 256; b = b2o; att = a2o; }
    __shared__ float gs[100];
    __shared__ float red[128];
    int j = threadIdx.x; // 128 threads
    if (j < 100) gs[j] = g[(size_t)r * 100 + j];
    __syncthreads();
    float acc = b[j];
    #pragma unroll 4
    for (int k = 0; k < 100; ++k) acc += gs[k] * W[(size_t)j * ld + off + k];
    Pg[((size_t)t * R_REL + r) * 128 + j] = acc;
    red[j] = att[j] * acc;
    __syncthreads();
    if (j < 2){
        float s = 0.f;
        for (int k = 0; k < 64; ++k) s += red[j * 64 + k];
        qg[((size_t)t * R_REL + r) * 2 + j] = s;
    }
}

// ---------------- g_prime = g @ Wr^T + br -> out (f32) ----------------
__global__ void k_gprime(const float* __restrict__ g, const float* __restrict__ Wr,
                         const float* __restrict__ br, float* __restrict__ out){
    int r = blockIdx.x, j = threadIdx.x; // 128 threads
    __shared__ float gs[100];
    if (j < 100) gs[j] = g[(size_t)r * 100 + j];
    __syncthreads();
    float acc = br[j];
    #pragma unroll 4
    for (int k = 0; k < 100; ++k) acc += gs[k] * Wr[(size_t)j * 100 + k];
    out[(size_t)N_NODES * 128 + (size_t)r * 128 + j] = acc;
}

// ---------------- node GEMM: C[M,NN] = A[M,128] @ W[NN,128]^T ----------------
__launch_bounds__(256)
__global__ void k_gemm(const u16* __restrict__ A, const u16* __restrict__ W,
                       u16* __restrict__ C, int M, int NN){
    int l = threadIdx.x & 63, w = threadIdx.x >> 6;
    int rb = blockIdx.x * 64 + w * 16;
    int ar = rb + (l & 15); if (ar >= M) ar = M - 1;
    const u16* Ap = A + (size_t)ar * 128 + (l >> 4) * 8;
    short8v a0 = *(const short8v*)(Ap);
    short8v a1 = *(const short8v*)(Ap + 32);
    short8v a2 = *(const short8v*)(Ap + 64);
    short8v a3 = *(const short8v*)(Ap + 96);
    int ntc = NN >> 4;
    for (int nt = 0; nt < ntc; ++nt){
        const u16* Wp = W + (size_t)(nt * 16 + (l & 15)) * 128 + (l >> 4) * 8;
        short8v b0 = *(const short8v*)(Wp);
        short8v b1 = *(const short8v*)(Wp + 32);
        short8v b2 = *(const short8v*)(Wp + 64);
        short8v b3 = *(const short8v*)(Wp + 96);
        float4v acc = {0.f, 0.f, 0.f, 0.f};
        acc = __builtin_amdgcn_mfma_f32_16x16x32_bf16(a0, b0, acc, 0, 0, 0);
        acc = __builtin_amdgcn_mfma_f32_16x16x32_bf16(a1, b1, acc, 0, 0, 0);
        acc = __builtin_amdgcn_mfma_f32_16x16x32_bf16(a2, b2, acc, 0, 0, 0);
        acc = __builtin_amdgcn_mfma_f32_16x16x32_bf16(a3, b3, acc, 0, 0, 0);
        int cc = nt * 16 + (l & 15);
        int rr0 = rb + (l >> 4) * 4;
        #pragma unroll
        for (int r = 0; r < 4; ++r){
            int rr = rr0 + r;
            if (rr < M) C[(size_t)rr * NN + cc] = f2b(acc[r]);
        }
    }
}

// ---------------- per-node attention scalars ----------------
__global__ void k_qnode(const u16* __restrict__ NP, int stride,
                        const float* __restrict__ attI, const float* __restrict__ attO,
                        float* __restrict__ q){
    int wid = threadIdx.x >> 6, l = threadIdx.x & 63;
    int n = blockIdx.x * 4 + wid;
    if (n >= N_NODES) return;
    uint4 uv = *(const uint4*)(NP + (size_t)n * stride + (size_t)l * 8);
    int t = l >> 4, h = (l >> 3) & 1;
    const float* att = ((t < 2) ? attI : attO) + h * 64 + (l & 7) * 8;
    float s = bl(uv.x) * att[0] + bh(uv.x) * att[1] + bl(uv.y) * att[2] + bh(uv.y) * att[3]
            + bl(uv.z) * att[4] + bh(uv.z) * att[5] + bl(uv.w) * att[6] + bh(uv.w) * att[7];
    s += __shfl_xor(s, 1); s += __shfl_xor(s, 2); s += __shfl_xor(s, 4);
    if ((l & 7) == 0) q[(size_t)n * 8 + t * 2 + h] = s;
}

// ---------------- edge pass A: logits -> exp -> denominators ----------------
__global__ void k_edgeA(const int* __restrict__ ei, const int* __restrict__ ety,
                        const float* __restrict__ q,
                        const float* __restrict__ qgI, const float* __restrict__ qgO,
                        float* __restrict__ ee, float* __restrict__ dI, float* __restrict__ dO){
    int e = blockIdx.x * blockDim.x + threadIdx.x;
    if (e >= E_EDGES) return;
    int row = ei[e], col = ei[E_EDGES + e], et = ety[e];
    const float* qr = q + (size_t)row * 8;
    const float* qc = q + (size_t)col * 8;
    const float* gI = qgI + (size_t)et * 2;
    const float* gO = qgO + (size_t)et * 2;
    #pragma unroll
    for (int h = 0; h < 2; ++h){
        float ain = qr[h] + qc[2 + h] + gI[h];
        float ein = expf(lrelu(ain));
        ee[(size_t)e * 4 + h] = ein;
        unsafeAtomicAdd(&dI[(size_t)row * 2 + h], ein);
        float aout = qc[4 + h] + qr[6 + h] + gO[h];
        float eout = expf(lrelu(aout));
        ee[(size_t)e * 4 + 2 + h] = eout;
        unsafeAtomicAdd(&dO[(size_t)col * 2 + h], eout);
    }
}

// ---------------- CSR build: histogram / scan / scatter ----------------
__global__ void k_hist(const int* __restrict__ ei, u32* __restrict__ cnt){
    int e = blockIdx.x * blockDim.x + threadIdx.x;
    if (e >= E_EDGES) return;
    atomicAdd(&cnt[ei[E_EDGES + e]], 1u);          // in-aggregation key: col
    atomicAdd(&cnt[N_NODES + ei[e]], 1u);          // out-aggregation key: row
}

__launch_bounds__(1024)
__global__ void k_scan1(const u32* __restrict__ cnt, u32* __restrict__ off, u32* __restrict__ bsum){
    __shared__ u32 sh[1024];
    int t = threadIdx.x, b = blockIdx.x, idx = b * 1024 + t;
    u32 v = cnt[idx];
    sh[t] = v; __syncthreads();
    #pragma unroll
    for (int d = 1; d < 1024; d <<= 1){
        u32 add = (t >= d) ? sh[t - d] : 0;
        __syncthreads();
        sh[t] += add;
        __syncthreads();
    }
    off[idx] = sh[t] - v;                          // exclusive within block
    if (t == 1023) bsum[b] = sh[1023];
}

__global__ void k_scan2(u32* __restrict__ bsum){
    if (threadIdx.x == 0){
        u32 run = 0;
        for (int i = 0; i < SCAN_B; ++i){ u32 t = bsum[i]; bsum[i] = run; run += t; }
    }
}

__launch_bounds__(1024)
__global__ void k_scan3(u32* __restrict__ off, const u32* __restrict__ bsum){
    int idx = blockIdx.x * 1024 + threadIdx.x;
    off[idx] += bsum[blockIdx.x];
}

__global__ void k_scatter(const int* __restrict__ ei, const int* __restrict__ ety,
                          u32* __restrict__ cur, uint2* __restrict__ sorted){
    int e = blockIdx.x * blockDim.x + threadIdx.x;
    if (e >= E_EDGES) return;
    int row = ei[e], col = ei[E_EDGES + e];
    u32 et = (u32)ety[e];
    u32 p1 = atomicAdd(&cur[col], 1u);
    sorted[p1] = make_uint2((u32)row | (et << 20), (u32)e);
    u32 p2 = atomicAdd(&cur[N_NODES + row], 1u);
    sorted[p2] = make_uint2((u32)col | (et << 20), (u32)e);
}

// ---------------- fused gather-aggregate + node epilogue ----------------
// wave per node: in-list [off[n],off[n+1]), out-list [off[N+n],off[N+n+1])
__launch_bounds__(256)
__global__ void k_agg(const u32* __restrict__ off, const uint2* __restrict__ sorted,
                      const u16* __restrict__ NP, int stride,
                      const float* __restrict__ PgI, const float* __restrict__ PgO,
                      const float* __restrict__ ee,
                      const float* __restrict__ dI, const float* __restrict__ dO,
                      int final_stage,
                      const u16* __restrict__ NP1, const float* __restrict__ be,
                      u16* __restrict__ h1b, float* __restrict__ out){
    int wid = threadIdx.x >> 6, l = threadIdx.x & 63;
    int n = blockIdx.x * 4 + wid;
    if (n >= N_NODES) return;
    int h = l >> 5, d0 = l * 2;
    const u16* selfP = NP + (size_t)n * stride;
    u32 pbi = *(const u32*)(selfP + 128 + d0);
    u32 pbo = *(const u32*)(selfP + 384 + d0);

    // ---- in-direction: sum_e ai*(Pa_i[row]+Pg_i[et]) + (sum ai)*Pb_i[n] ----
    float a0 = 0.f, a1 = 0.f, sai = 0.f;
    {
        int s0 = off[n], s1 = off[n + 1];
        uint2 rec;
        if (s0 < s1) rec = sorted[s0];
        for (int p = s0; p < s1; ++p){
            uint2 nxt = (p + 1 < s1) ? sorted[p + 1] : rec;
            int other = rec.x & 0xFFFFF, et = rec.x >> 20, e = (int)rec.y;
            float ai = ee[(size_t)e * 4 + h] / dI[(size_t)other * 2 + h];
            u32 pa = *(const u32*)(NP + (size_t)other * stride + d0);
            float2 gI = *(const float2*)(PgI + (size_t)et * 128 + d0);
            a0 += ai * (bl(pa) + gI.x);
            a1 += ai * (bh(pa) + gI.y);
            sai += ai;
            rec = nxt;
        }
    }
    a0 += sai * bl(pbi);
    a1 += sai * bh(pbi);

    // ---- out-direction: sum_e ao*(Pa_o[col]+Pg_o[et]) + (sum ao)*Pb_o[n] ----
    float b0 = 0.f, b1 = 0.f, sao = 0.f;
    {
        int s0 = off[N_NODES + n], s1 = off[N_NODES + n + 1];
        uint2 rec;
        if (s0 < s1) rec = sorted[s0];
        for (int p = s0; p < s1; ++p){
            uint2 nxt = (p + 1 < s1) ? sorted[p + 1] : rec;
            int other = rec.x & 0xFFFFF, et = rec.x >> 20, e = (int)rec.y;
            float ao = ee[(size_t)e * 4 + 2 + h] / dO[(size_t)other * 2 + h];
            u32 pa = *(const u32*)(NP + (size_t)other * stride + 256 + d0);
            float2 gO = *(const float2*)(PgO + (size_t)et * 128 + d0);
            b0 += ao * (bl(pa) + gO.x);
            b1 += ao * (bh(pa) + gO.y);
            sao += ao;
            rec = nxt;
        }
    }
    b0 += sao * bl(pbo);
    b1 += sao * bh(pbo);

    // ---- node epilogue ----
    float vx = lrelu(0.5f * (a0 + b0));
    float vy = lrelu(0.5f * (a1 + b1));
    float ss = vx * vx + vy * vy;
    #pragma unroll
    for (int m = 16; m; m >>= 1) ss += __shfl_xor(ss, m);    // per-head (32-lane) reduce
    float s2 = 1.f / fmaxf(sqrtf(ss), 1e-12f);
    if (!final_stage){
        *(u32*)(h1b + (size_t)n * 128 + d0) = pk2(vx * s2, vy * s2);
    } else {
        float h20 = vx * s2, h21 = vy * s2;
        int o0 = d0 & 63;
        u32 ue = *(const u32*)(NP1 + (size_t)n * 576 + 512 + o0);
        float hp0 = bl(ue) + be[o0] + h20;
        float hp1 = bh(ue) + be[o0 + 1] + h21;
        float st = hp0 * hp0 + hp1 * hp1;
        #pragma unroll
        for (int m = 32; m; m >>= 1) st += __shfl_xor(st, m); // full 128-dim norm
        float s = 1.f / fmaxf(sqrtf(st), 1e-12f);
        float2 o; o.x = hp0 * s; o.y = hp1 * s;
        *(float2*)(out + (size_t)n * 128 + d0) = o;
    }
}

extern "C" void kernel_launch(void* const* d_in, const int* in_sizes, int n_in,
                              void* d_out, int out_size, void* d_ws, size_t ws_size,
                              hipStream_t stream){
    const float* x   = (const float*)d_in[0];
    const float* g   = (const float*)d_in[1];
    const int*   ei  = (const int*)d_in[2];
    const int*   ety = (const int*)d_in[3];
    const float* W1i = (const float*)d_in[4];
    const float* b1i = (const float*)d_in[5];
    const float* a1i = (const float*)d_in[6];
    const float* W1o = (const float*)d_in[7];
    const float* b1o = (const float*)d_in[8];
    const float* a1o = (const float*)d_in[9];
    const float* W2i = (const float*)d_in[10];
    const float* b2i = (const float*)d_in[11];
    const float* a2i = (const float*)d_in[12];
    const float* W2o = (const float*)d_in[13];
    const float* b2o = (const float*)d_in[14];
    const float* a2o = (const float*)d_in[15];
    const float* We  = (const float*)d_in[16];
    const float* be  = (const float*)d_in[17];
    const float* Wr  = (const float*)d_in[18];
    const float* br  = (const float*)d_in[19];
    float* out = (float*)d_out;

    char* ws = (char*)d_ws;
    size_t off_b = 0;
    auto carve = [&](size_t bytes) -> char* {
        char* p = ws + off_b;
        off_b += (bytes + 255) & ~(size_t)255;
        return p;
    };
    u16*   xnb  = (u16*)carve((size_t)N_NODES * 128 * 2);
    u16*   wc1  = (u16*)carve((size_t)576 * 128 * 2);
    u16*   wc2  = (u16*)carve((size_t)512 * 128 * 2);
    u16*   NP1  = (u16*)carve((size_t)N_NODES * 576 * 2);
    u16*   NP2  = (u16*)carve((size_t)N_NODES * 512 * 2);
    u16*   h1b  = (u16*)carve((size_t)N_NODES * 128 * 2);
    float* q    = (float*)carve((size_t)N_NODES * 8 * 4);
    float* Pg   = (float*)carve((size_t)4 * R_REL * 128 * 4);
    float* qg   = (float*)carve((size_t)4 * R_REL * 2 * 4);
    float* ee   = (float*)carve((size_t)E_EDGES * 4 * 4);
    u32*   cnt  = (u32*)carve((size_t)SCAN_B * 1024 * 4);     // zeroed, padded
    u32*   offA = (u32*)carve((size_t)SCAN_B * 1024 * 4);     // exclusive scan
    u32*   cur  = (u32*)carve((size_t)NKEYS * 4);             // scatter cursors
    u32*   bsum = (u32*)carve((size_t)SCAN_B * 4);
    uint2* srt  = (uint2*)carve((size_t)2 * E_EDGES * 8);
    // zero region: dI | dO
    size_t zbytes = (size_t)N_NODES * 2 * 4 * 2;
    char*  zreg = carve(zbytes);
    float* dI   = (float*)zreg;
    float* dO   = dI + (size_t)N_NODES * 2;

    // ---------------- stage 0: prep (CSR sort + tables + GEMM input) ----------------
    hipMemsetAsync(cnt, 0, (size_t)SCAN_B * 1024 * 4, stream);
    k_hist<<<1563, 256, 0, stream>>>(ei, cnt);
    k_scan1<<<SCAN_B, 1024, 0, stream>>>(cnt, offA, bsum);
    k_scan2<<<1, 64, 0, stream>>>(bsum);
    k_scan3<<<SCAN_B, 1024, 0, stream>>>(offA, bsum);
    hipMemcpyAsync(cur, offA, (size_t)NKEYS * 4, hipMemcpyDeviceToDevice, stream);
    k_scatter<<<1563, 256, 0, stream>>>(ei, ety, cur, srt);

    k_norm_x<<<12500, 256, 0, stream>>>(x, xnb);
    k_build_wcat<<<544, 256, 0, stream>>>(W1i, W1o, W2i, W2o, We, wc1, wc2);
    k_pg<<<2000, 128, 0, stream>>>(g, W1i, W1o, W2i, W2o, b1i, b1o, b2i, b2o,
                                   a1i, a1o, a2i, a2o, Pg, qg);
    k_gprime<<<500, 128, 0, stream>>>(g, Wr, br, out);

    // ---------------- stage 1 ----------------
    hipMemsetAsync(zreg, 0, zbytes, stream);
    k_gemm<<<782, 256, 0, stream>>>(xnb, wc1, NP1, N_NODES, 576);
    k_qnode<<<12500, 256, 0, stream>>>(NP1, 576, a1i, a1o, q);
    k_edgeA<<<1563, 256, 0, stream>>>(ei, ety, q, qg, qg + R_REL * 2, ee, dI, dO);
    k_agg<<<12500, 256, 0, stream>>>(offA, srt, NP1, 576, Pg, Pg + R_REL * 128,
                                     ee, dI, dO, 0, NP1, be, h1b, out);

    // ---------------- stage 2 ----------------
    hipMemsetAsync(zreg, 0, zbytes, stream);
    k_gemm<<<782, 256, 0, stream>>>(h1b, wc2, NP2, N_NODES, 512);
    k_qnode<<<12500, 256, 0, stream>>>(NP2, 512, a2i, a2o, q);
    k_edgeA<<<1563, 256, 0, stream>>>(ei, ety, q, qg + 2 * R_REL * 2, qg + 3 * R_REL * 2,
                                      ee, dI, dO);
    k_agg<<<12500, 256, 0, stream>>>(offA, srt, NP2, 512, Pg + 2 * R_REL * 128,
                                     Pg + 3 * R_REL * 128, ee, dI, dO, 1, NP1, be, h1b, out);
}

// Round 4
// 613.898 us; speedup vs baseline: 2.7837x; 1.1959x over previous
//
#include <hip/hip_runtime.h>

typedef unsigned short u16;
typedef unsigned int u32;
typedef short short8v __attribute__((ext_vector_type(8)));
typedef float float4v __attribute__((ext_vector_type(4)));

#define N_NODES 50000
#define E_EDGES 400000
#define R_REL   500
#define NKEYS   100000          // cntI[50000] | cntO[50000]
#define SCAN_B  98              // 98*1024 = 100352 >= NKEYS

__device__ __forceinline__ float bl(u32 u){ return __uint_as_float(u << 16); }
__device__ __forceinline__ float bh(u32 u){ return __uint_as_float(u & 0xffff0000u); }
__device__ __forceinline__ u16 f2b(float f){
    u32 u = __float_as_uint(f);
    return (u16)((u + 0x7fffu + ((u >> 16) & 1u)) >> 16);
}
__device__ __forceinline__ u32 pk2(float a, float b){ return (u32)f2b(a) | ((u32)f2b(b) << 16); }
__device__ __forceinline__ float lrelu(float x){ return x > 0.f ? x : 0.01f * x; }

// ---------------- normalize x -> bf16 padded [N,128] ----------------
__global__ void k_norm_x(const float* __restrict__ x, u16* __restrict__ xnb){
    int wid = threadIdx.x >> 6, l = threadIdx.x & 63;
    int n = blockIdx.x * 4 + wid;
    if (n >= N_NODES) return;
    float v0 = x[(size_t)n * 100 + l];
    float v1 = (l + 64 < 100) ? x[(size_t)n * 100 + 64 + l] : 0.f;
    float ss = v0 * v0 + v1 * v1;
    #pragma unroll
    for (int m = 32; m; m >>= 1) ss += __shfl_xor(ss, m);
    float s = 1.f / fmaxf(sqrtf(ss), 1e-12f);
    xnb[(size_t)n * 128 + l] = f2b(v0 * s);
    xnb[(size_t)n * 128 + 64 + l] = (l + 64 < 100) ? f2b(v1 * s) : (u16)0;
}

// ---------------- build concatenated weight matrices (bf16) ----------------
__global__ void k_build_wcat(const float* __restrict__ W1i, const float* __restrict__ W1o,
                             const float* __restrict__ W2i, const float* __restrict__ W2o,
                             const float* __restrict__ We,
                             u16* __restrict__ wc1, u16* __restrict__ wc2){
    int idx = blockIdx.x * blockDim.x + threadIdx.x;
    if (idx < 576 * 128){
        int r = idx >> 7, k = idx & 127;
        float v = 0.f;
        if (r < 512){
            int seg = r >> 7, rr = r & 127;
            const float* W = (seg < 2) ? W1i : W1o;
            int off = (seg & 1) ? 100 : 0;
            if (k < 100) v = W[(size_t)rr * 300 + off + k];
        } else {
            int rr = r - 512;
            if (k < 100) v = We[(size_t)rr * 100 + k];
        }
        wc1[idx] = f2b(v);
    } else if (idx < 576 * 128 + 512 * 128){
        int j = idx - 576 * 128;
        int r = j >> 7, k = j & 127;
        int seg = r >> 7, rr = r & 127;
        const float* W = (seg < 2) ? W2i : W2o;
        int off = (seg & 1) ? 128 : 0;
        wc2[j] = f2b(W[(size_t)rr * 356 + off + k]);
    }
}

// ---------------- relation tables ----------------
__global__ void k_pg(const float* __restrict__ g,
                     const float* __restrict__ W1i, const float* __restrict__ W1o,
                     const float* __restrict__ W2i, const float* __restrict__ W2o,
                     const float* __restrict__ b1i, const float* __restrict__ b1o,
                     const float* __restrict__ b2i, const float* __restrict__ b2o,
                     const float* __restrict__ a1i, const float* __restrict__ a1o,
                     const float* __restrict__ a2i, const float* __restrict__ a2o,
                     float* __restrict__ Pg, float* __restrict__ qg){
    int bid = blockIdx.x;
    int r = bid >> 2, t = bid & 3;
    const float *W, *b, *att; int ld, off;
    if (t == 0){ W = W1i; ld = 300; off = 200; b = b1i; att = a1i; }
    else if (t == 1){ W = W1o; ld = 300; off = 200; b = b1o; att = a1o; }
    else if (t == 2){ W = W2i; ld = 356; off = 256; b = b2i; att = a2i; }
    else { W = W2o; ld = 356; off = 256; b = b2o; att = a2o; }
    __shared__ float gs[100];
    __shared__ float red[128];
    int j = threadIdx.x; // 128 threads
    if (j < 100) gs[j] = g[(size_t)r * 100 + j];
    __syncthreads();
    float acc = b[j];
    #pragma unroll 4
    for (int k = 0; k < 100; ++k) acc += gs[k] * W[(size_t)j * ld + off + k];
    Pg[((size_t)t * R_REL + r) * 128 + j] = acc;
    red[j] = att[j] * acc;
    __syncthreads();
    if (j < 2){
        float s = 0.f;
        for (int k = 0; k < 64; ++k) s += red[j * 64 + k];
        qg[((size_t)t * R_REL + r) * 2 + j] = s;
    }
}

// ---------------- g_prime = g @ Wr^T + br -> out (f32) ----------------
__global__ void k_gprime(const float* __restrict__ g, const float* __restrict__ Wr,
                         const float* __restrict__ br, float* __restrict__ out){
    int r = blockIdx.x, j = threadIdx.x; // 128 threads
    __shared__ float gs[100];
    if (j < 100) gs[j] = g[(size_t)r * 100 + j];
    __syncthreads();
    float acc = br[j];
    #pragma unroll 4
    for (int k = 0; k < 100; ++k) acc += gs[k] * Wr[(size_t)j * 100 + k];
    out[(size_t)N_NODES * 128 + (size_t)r * 128 + j] = acc;
}

// ---------------- node GEMM: C[M,NN] = A[M,128] @ W[NN,128]^T ----------------
__launch_bounds__(256)
__global__ void k_gemm(const u16* __restrict__ A, const u16* __restrict__ W,
                       u16* __restrict__ C, int M, int NN){
    int l = threadIdx.x & 63, w = threadIdx.x >> 6;
    int rb = blockIdx.x * 64 + w * 16;
    int ar = rb + (l & 15); if (ar >= M) ar = M - 1;
    const u16* Ap = A + (size_t)ar * 128 + (l >> 4) * 8;
    short8v a0 = *(const short8v*)(Ap);
    short8v a1 = *(const short8v*)(Ap + 32);
    short8v a2 = *(const short8v*)(Ap + 64);
    short8v a3 = *(const short8v*)(Ap + 96);
    int ntc = NN >> 4;
    for (int nt = 0; nt < ntc; ++nt){
        const u16* Wp = W + (size_t)(nt * 16 + (l & 15)) * 128 + (l >> 4) * 8;
        short8v b0 = *(const short8v*)(Wp);
        short8v b1 = *(const short8v*)(Wp + 32);
        short8v b2 = *(const short8v*)(Wp + 64);
        short8v b3 = *(const short8v*)(Wp + 96);
        float4v acc = {0.f, 0.f, 0.f, 0.f};
        acc = __builtin_amdgcn_mfma_f32_16x16x32_bf16(a0, b0, acc, 0, 0, 0);
        acc = __builtin_amdgcn_mfma_f32_16x16x32_bf16(a1, b1, acc, 0, 0, 0);
        acc = __builtin_amdgcn_mfma_f32_16x16x32_bf16(a2, b2, acc, 0, 0, 0);
        acc = __builtin_amdgcn_mfma_f32_16x16x32_bf16(a3, b3, acc, 0, 0, 0);
        int cc = nt * 16 + (l & 15);
        int rr0 = rb + (l >> 4) * 4;
        #pragma unroll
        for (int r = 0; r < 4; ++r){
            int rr = rr0 + r;
            if (rr < M) C[(size_t)rr * NN + cc] = f2b(acc[r]);
        }
    }
}

// ---------------- per-node attention scalars ----------------
__global__ void k_qnode(const u16* __restrict__ NP, int stride,
                        const float* __restrict__ attI, const float* __restrict__ attO,
                        float* __restrict__ q){
    int wid = threadIdx.x >> 6, l = threadIdx.x & 63;
    int n = blockIdx.x * 4 + wid;
    if (n >= N_NODES) return;
    uint4 uv = *(const uint4*)(NP + (size_t)n * stride + (size_t)l * 8);
    int t = l >> 4, h = (l >> 3) & 1;
    const float* att = ((t < 2) ? attI : attO) + h * 64 + (l & 7) * 8;
    float s = bl(uv.x) * att[0] + bh(uv.x) * att[1] + bl(uv.y) * att[2] + bh(uv.y) * att[3]
            + bl(uv.z) * att[4] + bh(uv.z) * att[5] + bl(uv.w) * att[6] + bh(uv.w) * att[7];
    s += __shfl_xor(s, 1); s += __shfl_xor(s, 2); s += __shfl_xor(s, 4);
    if ((l & 7) == 0) q[(size_t)n * 8 + t * 2 + h] = s;
}

// ---------------- CSR build: histogram / scan / positions ----------------
__global__ void k_hist(const int* __restrict__ ei, u32* __restrict__ cnt){
    int e = blockIdx.x * blockDim.x + threadIdx.x;
    if (e >= E_EDGES) return;
    atomicAdd(&cnt[ei[E_EDGES + e]], 1u);          // in-aggregation key: col
    atomicAdd(&cnt[N_NODES + ei[e]], 1u);          // out-aggregation key: row
}

__launch_bounds__(1024)
__global__ void k_scan1(const u32* __restrict__ cnt, u32* __restrict__ off, u32* __restrict__ bsum){
    __shared__ u32 sh[1024];
    int t = threadIdx.x, b = blockIdx.x, idx = b * 1024 + t;
    u32 v = cnt[idx];
    sh[t] = v; __syncthreads();
    #pragma unroll
    for (int d = 1; d < 1024; d <<= 1){
        u32 add = (t >= d) ? sh[t - d] : 0;
        __syncthreads();
        sh[t] += add;
        __syncthreads();
    }
    off[idx] = sh[t] - v;                          // exclusive within block
    if (t == 1023) bsum[b] = sh[1023];
}

__global__ void k_scan2(u32* __restrict__ bsum){
    if (threadIdx.x == 0){
        u32 run = 0;
        for (int i = 0; i < SCAN_B; ++i){ u32 t = bsum[i]; bsum[i] = run; run += t; }
    }
}

__launch_bounds__(1024)
__global__ void k_scan3(u32* __restrict__ off, const u32* __restrict__ bsum){
    int idx = blockIdx.x * 1024 + threadIdx.x;
    off[idx] += bsum[blockIdx.x];
}

// per-edge sorted positions (once)
__global__ void k_pos(const int* __restrict__ ei, u32* __restrict__ cur,
                      u32* __restrict__ posI, u32* __restrict__ posO){
    int e = blockIdx.x * blockDim.x + threadIdx.x;
    if (e >= E_EDGES) return;
    posI[e] = atomicAdd(&cur[ei[E_EDGES + e]], 1u);
    posO[e] = atomicAdd(&cur[N_NODES + ei[e]], 1u);
}

// ---------------- edge pass A: logits -> exp -> denoms + sorted records ----------------
// record: {other | et<<20, exp_h0, exp_h1, pad}
__global__ void k_edgeA(const int* __restrict__ ei, const int* __restrict__ ety,
                        const float* __restrict__ q,
                        const float* __restrict__ qgI, const float* __restrict__ qgO,
                        const u32* __restrict__ posI, const u32* __restrict__ posO,
                        uint4* __restrict__ srt,
                        float* __restrict__ dI, float* __restrict__ dO){
    int e = blockIdx.x * blockDim.x + threadIdx.x;
    if (e >= E_EDGES) return;
    int row = ei[e], col = ei[E_EDGES + e], et = ety[e];
    const float* qr = q + (size_t)row * 8;
    const float* qc = q + (size_t)col * 8;
    const float* gI = qgI + (size_t)et * 2;
    const float* gO = qgO + (size_t)et * 2;
    float ein0 = expf(lrelu(qr[0] + qc[2] + gI[0]));
    float ein1 = expf(lrelu(qr[1] + qc[3] + gI[1]));
    float eo0  = expf(lrelu(qc[4] + qr[6] + gO[0]));
    float eo1  = expf(lrelu(qc[5] + qr[7] + gO[1]));
    unsafeAtomicAdd(&dI[(size_t)row * 2 + 0], ein0);
    unsafeAtomicAdd(&dI[(size_t)row * 2 + 1], ein1);
    unsafeAtomicAdd(&dO[(size_t)col * 2 + 0], eo0);
    unsafeAtomicAdd(&dO[(size_t)col * 2 + 1], eo1);
    u32 etb = (u32)et << 20;
    srt[posI[e]] = make_uint4((u32)row | etb, __float_as_uint(ein0), __float_as_uint(ein1), 0u);
    srt[posO[e]] = make_uint4((u32)col | etb, __float_as_uint(eo0),  __float_as_uint(eo1),  0u);
}

// invert denominators in place (dI|dO contiguous)
__global__ void k_inv(float* __restrict__ d){
    int i = blockIdx.x * blockDim.x + threadIdx.x;
    if (i < NKEYS * 2) d[i] = 1.f / d[i];
}

// ---------------- fused gather-aggregate + node epilogue ----------------
__launch_bounds__(256)
__global__ void k_agg(const u32* __restrict__ off, const uint4* __restrict__ srt,
                      const u16* __restrict__ NP, int stride,
                      const float* __restrict__ PgI, const float* __restrict__ PgO,
                      const float* __restrict__ dI, const float* __restrict__ dO,
                      int final_stage,
                      const u16* __restrict__ NP1, const float* __restrict__ be,
                      u16* __restrict__ h1b, float* __restrict__ out){
    int wid = threadIdx.x >> 6, l = threadIdx.x & 63;
    int n = blockIdx.x * 4 + wid;
    if (n >= N_NODES) return;
    int h = l >> 5, d0 = l * 2;
    const u16* selfP = NP + (size_t)n * stride;
    u32 pbi = *(const u32*)(selfP + 128 + d0);
    u32 pbo = *(const u32*)(selfP + 384 + d0);

    float a0 = 0.f, a1 = 0.f, sai = 0.f;
    {
        u32 s0 = off[n], s1 = off[n + 1], p = s0;
        #define IN_EDGE(r) { \
            u32 oth = r.x & 0xFFFFF; u32 et = r.x >> 20; \
            float ai = __uint_as_float(h ? r.z : r.y) * dI[(size_t)oth * 2 + h]; \
            u32 pa = *(const u32*)(NP + (size_t)oth * stride + d0); \
            float2 gv = *(const float2*)(PgI + (size_t)et * 128 + d0); \
            a0 += ai * (bl(pa) + gv.x); a1 += ai * (bh(pa) + gv.y); sai += ai; }
        for (; p + 4 <= s1; p += 4){
            uint4 r0 = srt[p], r1 = srt[p+1], r2 = srt[p+2], r3 = srt[p+3];
            IN_EDGE(r0) IN_EDGE(r1) IN_EDGE(r2) IN_EDGE(r3)
        }
        for (; p < s1; ++p){ uint4 r = srt[p]; IN_EDGE(r) }
        #undef IN_EDGE
    }
    a0 += sai * bl(pbi);
    a1 += sai * bh(pbi);

    float b0 = 0.f, b1 = 0.f, sao = 0.f;
    {
        u32 s0 = off[N_NODES + n], s1 = off[N_NODES + n + 1], p = s0;
        #define OUT_EDGE(r) { \
            u32 oth = r.x & 0xFFFFF; u32 et = r.x >> 20; \
            float ao = __uint_as_float(h ? r.z : r.y) * dO[(size_t)oth * 2 + h]; \
            u32 pa = *(const u32*)(NP + (size_t)oth * stride + 256 + d0); \
            float2 gv = *(const float2*)(PgO + (size_t)et * 128 + d0); \
            b0 += ao * (bl(pa) + gv.x); b1 += ao * (bh(pa) + gv.y); sao += ao; }
        for (; p + 4 <= s1; p += 4){
            uint4 r0 = srt[p], r1 = srt[p+1], r2 = srt[p+2], r3 = srt[p+3];
            OUT_EDGE(r0) OUT_EDGE(r1) OUT_EDGE(r2) OUT_EDGE(r3)
        }
        for (; p < s1; ++p){ uint4 r = srt[p]; OUT_EDGE(r) }
        #undef OUT_EDGE
    }
    b0 += sao * bl(pbo);
    b1 += sao * bh(pbo);

    float vx = lrelu(0.5f * (a0 + b0));
    float vy = lrelu(0.5f * (a1 + b1));
    float ss = vx * vx + vy * vy;
    #pragma unroll
    for (int m = 16; m; m >>= 1) ss += __shfl_xor(ss, m);    // per-head (32-lane) reduce
    float s2 = 1.f / fmaxf(sqrtf(ss), 1e-12f);
    if (!final_stage){
        *(u32*)(h1b + (size_t)n * 128 + d0) = pk2(vx * s2, vy * s2);
    } else {
        float h20 = vx * s2, h21 = vy * s2;
        int o0 = d0 & 63;
        u32 ue = *(const u32*)(NP1 + (size_t)n * 576 + 512 + o0);
        float hp0 = bl(ue) + be[o0] + h20;
        float hp1 = bh(ue) + be[o0 + 1] + h21;
        float st = hp0 * hp0 + hp1 * hp1;
        #pragma unroll
        for (int m = 32; m; m >>= 1) st += __shfl_xor(st, m); // full 128-dim norm
        float s = 1.f / fmaxf(sqrtf(st), 1e-12f);
        float2 o; o.x = hp0 * s; o.y = hp1 * s;
        *(float2*)(out + (size_t)n * 128 + d0) = o;
    }
}

extern "C" void kernel_launch(void* const* d_in, const int* in_sizes, int n_in,
                              void* d_out, int out_size, void* d_ws, size_t ws_size,
                              hipStream_t stream){
    const float* x   = (const float*)d_in[0];
    const float* g   = (const float*)d_in[1];
    const int*   ei  = (const int*)d_in[2];
    const int*   ety = (const int*)d_in[3];
    const float* W1i = (const float*)d_in[4];
    const float* b1i = (const float*)d_in[5];
    const float* a1i = (const float*)d_in[6];
    const float* W1o = (const float*)d_in[7];
    const float* b1o = (const float*)d_in[8];
    const float* a1o = (const float*)d_in[9];
    const float* W2i = (const float*)d_in[10];
    const float* b2i = (const float*)d_in[11];
    const float* a2i = (const float*)d_in[12];
    const float* W2o = (const float*)d_in[13];
    const float* b2o = (const float*)d_in[14];
    const float* a2o = (const float*)d_in[15];
    const float* We  = (const float*)d_in[16];
    const float* be  = (const float*)d_in[17];
    const float* Wr  = (const float*)d_in[18];
    const float* br  = (const float*)d_in[19];
    float* out = (float*)d_out;

    char* ws = (char*)d_ws;
    size_t off_b = 0;
    auto carve = [&](size_t bytes) -> char* {
        char* p = ws + off_b;
        off_b += (bytes + 255) & ~(size_t)255;
        return p;
    };
    u16*   xnb  = (u16*)carve((size_t)N_NODES * 128 * 2);
    u16*   wc1  = (u16*)carve((size_t)576 * 128 * 2);
    u16*   wc2  = (u16*)carve((size_t)512 * 128 * 2);
    u16*   NP1  = (u16*)carve((size_t)N_NODES * 576 * 2);
    u16*   NP2  = (u16*)carve((size_t)N_NODES * 512 * 2);
    u16*   h1b  = (u16*)carve((size_t)N_NODES * 128 * 2);
    float* q    = (float*)carve((size_t)N_NODES * 8 * 4);
    float* Pg   = (float*)carve((size_t)4 * R_REL * 128 * 4);
    float* qg   = (float*)carve((size_t)4 * R_REL * 2 * 4);
    u32*   cnt  = (u32*)carve((size_t)SCAN_B * 1024 * 4);     // zeroed, padded
    u32*   offA = (u32*)carve((size_t)SCAN_B * 1024 * 4);     // exclusive scan
    u32*   cur  = (u32*)carve((size_t)NKEYS * 4);             // position cursors
    u32*   bsum = (u32*)carve((size_t)SCAN_B * 4);
    u32*   posI = (u32*)carve((size_t)E_EDGES * 4);
    u32*   posO = (u32*)carve((size_t)E_EDGES * 4);
    uint4* srt  = (uint4*)carve((size_t)2 * E_EDGES * 16);
    // zero region: dI | dO
    size_t zbytes = (size_t)NKEYS * 2 * 4;
    char*  zreg = carve(zbytes);
    float* dI   = (float*)zreg;
    float* dO   = dI + (size_t)N_NODES * 2;

    // ---------------- stage 0: prep (CSR positions + tables + GEMM input) ----------------
    hipMemsetAsync(cnt, 0, (size_t)SCAN_B * 1024 * 4, stream);
    k_hist<<<1563, 256, 0, stream>>>(ei, cnt);
    k_scan1<<<SCAN_B, 1024, 0, stream>>>(cnt, offA, bsum);
    k_scan2<<<1, 64, 0, stream>>>(bsum);
    k_scan3<<<SCAN_B, 1024, 0, stream>>>(offA, bsum);
    hipMemcpyAsync(cur, offA, (size_t)NKEYS * 4, hipMemcpyDeviceToDevice, stream);
    k_pos<<<1563, 256, 0, stream>>>(ei, cur, posI, posO);

    k_norm_x<<<12500, 256, 0, stream>>>(x, xnb);
    k_build_wcat<<<544, 256, 0, stream>>>(W1i, W1o, W2i, W2o, We, wc1, wc2);
    k_pg<<<2000, 128, 0, stream>>>(g, W1i, W1o, W2i, W2o, b1i, b1o, b2i, b2o,
                                   a1i, a1o, a2i, a2o, Pg, qg);
    k_gprime<<<500, 128, 0, stream>>>(g, Wr, br, out);

    // ---------------- stage 1 ----------------
    hipMemsetAsync(zreg, 0, zbytes, stream);
    k_gemm<<<782, 256, 0, stream>>>(xnb, wc1, NP1, N_NODES, 576);
    k_qnode<<<12500, 256, 0, stream>>>(NP1, 576, a1i, a1o, q);
    k_edgeA<<<1563, 256, 0, stream>>>(ei, ety, q, qg, qg + R_REL * 2,
                                      posI, posO, srt, dI, dO);
    k_inv<<<782, 256, 0, stream>>>(dI);
    k_agg<<<12500, 256, 0, stream>>>(offA, srt, NP1, 576, Pg, Pg + R_REL * 128,
                                     dI, dO, 0, NP1, be, h1b, out);

    // ---------------- stage 2 ----------------
    hipMemsetAsync(zreg, 0, zbytes, stream);
    k_gemm<<<782, 256, 0, stream>>>(h1b, wc2, NP2, N_NODES, 512);
    k_qnode<<<12500, 256, 0, stream>>>(NP2, 512, a2i, a2o, q);
    k_edgeA<<<1563, 256, 0, stream>>>(ei, ety, q, qg + 2 * R_REL * 2, qg + 3 * R_REL * 2,
                                      posI, posO, srt, dI, dO);
    k_inv<<<782, 256, 0, stream>>>(dI);
    k_agg<<<12500, 256, 0, stream>>>(offA, srt, NP2, 512, Pg + 2 * R_REL * 128,
                                     Pg + 3 * R_REL * 128, dI, dO, 1, NP1, be, h1b, out);
}